// Round 6
// baseline (471.565 us; speedup 1.0000x reference)
//
#include <hip/hip_runtime.h>
#include <cstdint>
#include <cstddef>

// Problem constants (reference: B=4, T=4096, E=1024, M=E/2=512)
#define Tdim 4096
#define Bdim 4
#define Edim 1024
#define Mdim 512
#define EPSF 1e-6f
#define NTILES 1056  // sum over p of (64-2p) = S(32), panels store only k>=i0

typedef __bf16 bf16x8 __attribute__((ext_vector_type(8)));
typedef float f32x4 __attribute__((ext_vector_type(4)));

// S(p) = number of k64-tiles in panels [0,p) = p*(65-p)
__host__ __device__ __forceinline__ int panel_start(int p) { return p * (65 - p); }

// float -> bf16 bits, round-to-nearest-even (used in extract path)
__device__ __forceinline__ unsigned short f2bf(float f) {
  union { float f; unsigned int u; } a; a.f = f;
  unsigned int r = a.u + 0x7fffu + ((a.u >> 16) & 1u);
  return (unsigned short)(r >> 16);
}

// pack two f32 -> bf16x2 (round-half-up; 0.5-ulp bound, ties negligible here)
__device__ __forceinline__ unsigned int pack_bf16(float a, float b) {
  union { float f; unsigned int u; } ua, ub; ua.f = a; ub.f = b;
  // dst bytes [0,1,2,3] = [a.b2, a.b3, b.b2, b.b3]
  return __builtin_amdgcn_perm(ub.u + 0x8000u, ua.u + 0x8000u, 0x07060302u);
}

// bump kernel g(u) = exp(1 - 1/(1-u^2+eps)); reference's u>=1-EPS clamp can
// never fire for j<=T-1 (u_max = 1 - 1/horizon), so it is omitted.
__device__ __forceinline__ float kernel_g(float dj, float inv_h) {
  float u = fminf(dj * inv_h, 1.0f - EPSF);
  return __expf(1.0f - 1.0f / (1.0f - u * u + EPSF));
}

typedef void __attribute__((address_space(1)))* gas1;
typedef void __attribute__((address_space(3)))* las3;
// async global->LDS, 16B per lane; LDS dest = wave-uniform base + lane*16
__device__ __forceinline__ void load_lds16(const void* g, void* l) {
  __builtin_amdgcn_global_load_lds((gas1)(g), (las3)(l), 16, 0, 0);
}

// ---------------- prep: row sums (inv_s) AND Xc transpose ----------------
// grid 8192 x 256. Blocks [0,4096): rowsum only. Blocks [4096,8192):
// extract tile -> XcT[b][m][j] = bf16(x[b][j][2m]). (R3/R4-verified.)
__global__ __launch_bounds__(256) void prep_kernel(const float* __restrict__ x,
                                                   float* __restrict__ inv_s,
                                                   unsigned short* __restrict__ XcT) {
  __shared__ float smem[1104];  // extract: [0..1087] as ushort[32][68]; rowsum: [1088..1091]
  const int tid = threadIdx.x;
  const int id = blockIdx.x;
  if (id < Tdim) {
    // ---- rowsum for K row i (same summation order as R0 -> identical bits) ----
    const int i = id;
    const float inv_h = __fdividef(1.0f, (float)(Tdim - i));
    float s = 0.0f;
    for (int j = i + tid; j < Tdim; j += 256)
      s += kernel_g((float)(j - i), inv_h);
#pragma unroll
    for (int off = 32; off; off >>= 1) s += __shfl_down(s, off);
    if ((tid & 63) == 0) smem[1088 + (tid >> 6)] = s;
    __syncthreads();
    if (tid == 0)
      inv_s[i] = __fdividef(
          1.0f, fmaxf(smem[1088] + smem[1089] + smem[1090] + smem[1091], EPSF));
  } else {
    // ---- extract tile: 64 j x 32 m ----
    const int eid = id - Tdim;
    const int j0 = (eid & 63) * 64;
    const int m0 = ((eid >> 6) & 15) * 32;
    const int b  = eid >> 10;
    unsigned short* Ls = reinterpret_cast<unsigned short*>(smem);  // [32][68]
    const int q = tid & 15;        // float4 chunk along e
    const int jbase = tid >> 4;    // 0..15
#pragma unroll
    for (int it = 0; it < 4; ++it) {
      const int jj = jbase + it * 16;
      const size_t off = ((size_t)(b * Tdim + j0 + jj)) * Edim + 2 * m0 + 4 * q;
      const float4 v = *reinterpret_cast<const float4*>(&x[off]);
      Ls[(2 * q) * 68 + jj]     = f2bf(v.x);   // even channel of m0+2q
      Ls[(2 * q + 1) * 68 + jj] = f2bf(v.z);   // even channel of m0+2q+1
    }
    __syncthreads();
    const int ch = tid & 15;
    const int mb = tid >> 4;
#pragma unroll
    for (int it = 0; it < 2; ++it) {
      const int m = mb + it * 16;
      ushort4 uv;
      uv.x = Ls[m * 68 + 4 * ch];
      uv.y = Ls[m * 68 + 4 * ch + 1];
      uv.z = Ls[m * 68 + 4 * ch + 2];
      uv.w = Ls[m * 68 + 4 * ch + 3];
      *reinterpret_cast<ushort4*>(
          &XcT[((size_t)(b * Mdim + m0 + m)) * Tdim + j0 + 4 * ch]) = uv;
    }
  }
}

// ---------------- packK: K in MFMA-fragment order (R3-verified, unchanged) --------
__global__ __launch_bounds__(256) void packK_kernel(const float* __restrict__ inv_s,
                                                    unsigned short* __restrict__ Kswz) {
  const int id = blockIdx.x;  // 0..NTILES-1
  int p = 0;
  while (id >= (p + 1) * (64 - p)) ++p;   // S(p+1) = (p+1)*(64-p)
  const int jt = id - panel_start(p);
  const int i0 = p * 128;
  const int jb0 = i0 + jt * 64;
  unsigned short* dst = Kswz + (size_t)id * 8192;  // 16 KB per (p,jt) tile
  const int tid = threadIdx.x;
#pragma unroll
  for (int ss = 0; ss < 4; ++ss) {
    const int G = ss * 256 + tid;          // chunk index 0..1023
    const int lane = G & 63;
    const int kk = (G >> 6) & 1;
    const int r  = (G >> 7) & 3;
    const int h  = G >> 9;
    const int li = h * 64 + r * 16 + (lane & 15);
    const int i  = i0 + li;
    const float inv_h = __fdividef(1.0f, (float)(Tdim - i));
    const float sinv = inv_s[i];
    const int jb = jb0 + (kk * 4 + (lane >> 4)) * 8;
    float v[8];
#pragma unroll
    for (int e = 0; e < 8; ++e) {
      const int j = jb + e;
      v[e] = (j >= i) ? kernel_g((float)(j - i), inv_h) * sinv : 0.0f;
    }
    uint4 pk;
    pk.x = pack_bf16(v[0], v[1]);
    pk.y = pack_bf16(v[2], v[3]);
    pk.z = pack_bf16(v[4], v[5]);
    pk.w = pack_bf16(v[6], v[7]);
    *reinterpret_cast<uint4*>(&dst[(size_t)G * 8]) = pk;
  }
}

// ---------------- GEMM: phi[b,i,m] = K[i,:] @ Xc[b,:,m], fused output write --------
// CROSS-BLOCK SPLIT-K, R4 block kept intact (256 thr / 4 waves / 104 VGPR --
// R5's regression was launch_bounds(512,4) capping VGPR at 64 -> full spill;
// NO min-waves bound here). Grid 1024: job (p, h, mb) computes k-tiles
// [h*nh,(h+1)*nh), nh = 32-p. Longest serial job 64 -> 32 iters, LDS
// 2 x 16 KB = 32 KB -> 4 blocks/CU (vs R4's 2): more TLP for the latency
// R4 exposed (163K cyc/CU vs 34K cyc MFMA content).
// id -> job map (round-robin CU = id%256 assumption, like R0's pairing):
// quarters q=id>>8, c=id&255, g=c>>3, e=c&7:
//   p = (q odd) ? 31-g : g;  h = q>>1;  mb = ((q&1)<<3)+e
// -> each CU's 4 jobs have lengths {32-g, 1+g, 32-g, 1+g} = 66 iters,
// exactly uniform; longest jobs first; partner (other h) = id+-512 -> same
// CU slot -> partial traffic likely stays in-XCD.
// Wait-free combine, zero extra workspace: each half publishes raw partials
// into out's dword slot (o + h) of its own tile (dead storage until the
// finisher overwrites). publish -> threadfence -> syncthreads -> tid0
// atomicAdd(flag). old==0: exit. old==1: finisher. A block that samples
// flag!=0 up front skips publishing and combines directly (acquire fence).
// Exactly one finisher per tile; no spinning; correct under any dispatch
// order / XCD placement (device-scope atomics + fences, G16).
// Per-iter schedule = R4's verified pieces: counted vmcnt(8) (drains B(t),
// leaves A(t)x8 in flight), raw s_barrier + sched_barrier(0), stage B(t+1),
// A(t+1) register ping-pong, uniform clamped tail loads.
__global__ __launch_bounds__(256) void gemm_kernel(
    const unsigned short* __restrict__ Kswz,
    const unsigned short* __restrict__ XcT,
    const float* __restrict__ x,
    const float* __restrict__ graw,
    float* __restrict__ out,
    int* __restrict__ flags) {
  __shared__ unsigned short Bs[2][128 * 64];  // XcT rows m0.., swizzled 16B slots
  __shared__ int role_sh;
  const int id = blockIdx.x;           // 0..1023
  const int qq = id >> 8;              // quarter
  const int cc = id & 255;
  const int g  = cc >> 3;
  const int e  = cc & 7;
  const int p  = (qq & 1) ? (31 - g) : g;
  const int h  = qq >> 1;              // k-half
  const int mb = ((qq & 1) << 3) + e;
  const int i0 = p * 128;
  const int m0 = (mb & 3) * 128;
  const int b  = mb >> 2;
  const int tid = threadIdx.x;
  const int w = tid >> 6;
  const int l = tid & 63;
  const int wr = w >> 1, wc = w & 1;
  const unsigned short* Brow = XcT + ((size_t)b * Mdim + m0) * Tdim;
  const int srow  = l >> 3;                   // row within 8-row group
  const int sslot = l & 7;                    // linear 16B slot this lane fills
  const int schunk = (sslot ^ srow) * 8;      // swizzled source chunk (bf16 units)
  // A panel base for this wave's row-half and lane (units: shorts).
  // Fragment (r,kk) of panel-relative k-tile tt is at Apan + tt*8192 + (r*2+kk)*512.
  const unsigned short* Apan =
      Kswz + (size_t)panel_start(p) * 8192 + (size_t)(wr * 8) * 512 + (size_t)l * 8;

  f32x4 acc[4][4] = {};
  const int nh = 32 - p;           // this job's trip count (>= 1)
  const int tbase = h * nh;        // job's first panel-relative k-tile
  const int lr16 = l & 15;
  const int kq = l >> 4;  // 0..3: which 16B chunk quarter of the k-dim

  // ---- prologue: B(0) FIRST (older in vmcnt order), then A(0). "" fences
  // stop the compiler reordering loads across group edges.
#pragma unroll
  for (int q = 0; q < 4; ++q) {
    const int rr = (w * 4 + q) * 8 + srow;
    load_lds16(Brow + (size_t)rr * Tdim + (i0 + tbase * 64 + schunk),
               &Bs[0][(w * 4 + q) * 512]);
  }
  asm volatile("" ::: "memory");
  bf16x8 af0[2][4], af1[2][4];
#pragma unroll
  for (int r = 0; r < 4; ++r) {
    af0[0][r] = *reinterpret_cast<const bf16x8*>(Apan + (size_t)tbase * 8192 + (r * 2 + 0) * 512);
    af0[1][r] = *reinterpret_cast<const bf16x8*>(Apan + (size_t)tbase * 8192 + (r * 2 + 1) * 512);
  }
  asm volatile("" ::: "memory");

  // Per-iter vmcnt math: at top of iter t, outstanding = B(t)x4 (older) +
  // A(t)x8 (younger). vmcnt(8) completes exactly B(t); A(t) stays in flight
  // (compiler inserts its own vmcnt before the first MFMA using afC).
#define GHALF(tc, afC, afN)                                                       \
  do {                                                                            \
    asm volatile("s_waitcnt vmcnt(8)" ::: "memory");                              \
    __builtin_amdgcn_s_barrier();                                                 \
    __builtin_amdgcn_sched_barrier(0);                                            \
    /* stage B(tc+1) (clamped dead write at tail keeps vmcnt uniform) */          \
    {                                                                             \
      const int ts = (tc) + 1;                                                    \
      const int tt = tbase + ((ts < nh) ? ts : nh - 1);                           \
      unsigned short* bdst = Bs[ts & 1];                                          \
      _Pragma("unroll")                                                           \
      for (int q = 0; q < 4; ++q) {                                               \
        const int rr = (w * 4 + q) * 8 + srow;                                    \
        load_lds16(Brow + (size_t)rr * Tdim + (i0 + tt * 64 + schunk),            \
                   &bdst[(w * 4 + q) * 512]);                                     \
      }                                                                           \
    }                                                                             \
    /* prefetch A(tc+1) into afN (clamped dead load at tail) */                   \
    {                                                                             \
      const int tpre = tbase + (((tc) + 1 < nh) ? (tc) + 1 : nh - 1);             \
      const unsigned short* Ap = Apan + (size_t)tpre * 8192;                      \
      _Pragma("unroll")                                                           \
      for (int r = 0; r < 4; ++r) {                                               \
        afN[0][r] = *reinterpret_cast<const bf16x8*>(Ap + (r * 2 + 0) * 512);     \
        afN[1][r] = *reinterpret_cast<const bf16x8*>(Ap + (r * 2 + 1) * 512);     \
      }                                                                           \
    }                                                                             \
    /* compute tile tc from Bs[tc&1] + afC */                                     \
    {                                                                             \
      const unsigned short* bsrc = Bs[(tc) & 1];                                  \
      _Pragma("unroll")                                                           \
      for (int kk = 0; kk < 2; ++kk) {                                            \
        bf16x8 bfr[4];                                                            \
        const int chunk = kk * 4 + kq;                                            \
        const int slot = (chunk ^ (lr16 & 7)) * 8; /* un-swizzle */               \
        _Pragma("unroll")                                                         \
        for (int c = 0; c < 4; ++c)                                               \
          bfr[c] = *reinterpret_cast<const bf16x8*>(                              \
              &bsrc[(wc * 64 + c * 16 + lr16) * 64 + slot]);                      \
        _Pragma("unroll")                                                         \
        for (int r = 0; r < 4; ++r)                                               \
          _Pragma("unroll")                                                       \
          for (int c = 0; c < 4; ++c)                                             \
            acc[r][c] = __builtin_amdgcn_mfma_f32_16x16x32_bf16(                  \
                afC[kk][r], bfr[c], acc[r][c], 0, 0, 0);                          \
      }                                                                           \
    }                                                                             \
  } while (0)

  for (int t = 0; t + 1 < nh; t += 2) {
    GHALF(t, af0, af1);
    GHALF(t + 1, af1, af0);
  }
  if (nh & 1) GHALF(nh - 1, af0, af1);
#undef GHALF

  // ---- wait-free split-k combine ----
  const int tile = (p << 4) | mb;
  const int lr = l & 15;
  const int lq = l >> 4;
  if (tid == 0)
    role_sh = (__hip_atomic_load(&flags[tile], __ATOMIC_RELAXED,
                                 __HIP_MEMORY_SCOPE_AGENT) != 0) ? 1 : 0;
  __syncthreads();
  int fin = role_sh;
  if (!fin) {
    // publish my raw partial into dword slot (o + h) of this tile
#pragma unroll
    for (int r = 0; r < 4; ++r) {
      const int ii = i0 + wr * 64 + r * 16 + lq * 4;
#pragma unroll
      for (int c = 0; c < 4; ++c) {
        const int m = m0 + wc * 64 + c * 16 + lr;
#pragma unroll
        for (int v = 0; v < 4; ++v) {
          const size_t o = ((size_t)(b * Tdim + ii + v)) * Edim + 2 * m;
          out[o + h] = acc[r][c][v];
        }
      }
    }
    __threadfence();   // release: my stores reach device scope
    __syncthreads();   // ...for ALL lanes, before the single flag bump
    if (tid == 0) role_sh = atomicAdd(&flags[tile], 1);
    __syncthreads();
    fin = role_sh;     // 0: partner not done -> it will finish; we exit
    if (!fin) return;
  }
  __threadfence();     // acquire: partner's slot stores visible
  const int ps = h ^ 1;  // partner's slot offset

  // fused epilogue: C/D layout col=lane&15 (m), row=(lane>>4)*4+reg (i).
  // out even = x even (exact fp32 passthrough), odd = (sum of halves)*softplus.
  float gm[4];
#pragma unroll
  for (int c = 0; c < 4; ++c) {
    const float v = graw[m0 + wc * 64 + c * 16 + lr];
    gm[c] = fmaxf(v, 0.0f) + __logf(1.0f + __expf(-fabsf(v)));  // stable softplus
  }
#pragma unroll
  for (int r = 0; r < 4; ++r) {
    const int ii = i0 + wr * 64 + r * 16 + lq * 4;
#pragma unroll
    for (int c = 0; c < 4; ++c) {
      const int m = m0 + wc * 64 + c * 16 + lr;
#pragma unroll
      for (int v = 0; v < 4; ++v) {
        const size_t o = ((size_t)(b * Tdim + ii + v)) * Edim + 2 * m;
        const float part = out[o + ps];
        const float2 xv = *reinterpret_cast<const float2*>(&x[o]);
        float2 res;
        res.x = xv.x;
        res.y = (acc[r][c][v] + part) * gm[c];
        *reinterpret_cast<float2*>(&out[o]) = res;
      }
    }
  }
}

// ---------------- slow-but-correct fallback (only if ws too small) ----------------
__global__ __launch_bounds__(256) void fallback_kernel(const float* __restrict__ x,
                                                       const float* __restrict__ graw,
                                                       float* __restrict__ out) {
  const int i = blockIdx.x, b = blockIdx.y, tid = threadIdx.x;
  const float inv_h = 1.0f / (float)(Tdim - i);
  float s = 0.0f;
  for (int j = i + tid; j < Tdim; j += 256)
    s += kernel_g((float)(j - i), inv_h);
#pragma unroll
  for (int off = 32; off; off >>= 1) s += __shfl_down(s, off);
  __shared__ float red[4];
  __shared__ float sinv_sh;
  if ((tid & 63) == 0) red[tid >> 6] = s;
  __syncthreads();
  if (tid == 0) sinv_sh = 1.0f / (red[0] + red[1] + red[2] + red[3]);
  __syncthreads();
  const float sinv = sinv_sh;
  const float* xb = x + (size_t)b * Tdim * Edim;
  float a0 = 0.0f, a1 = 0.0f;
  const int m0 = tid, m1 = tid + 256;
  for (int j = i; j < Tdim; ++j) {
    const float wgt = kernel_g((float)(j - i), inv_h);
    const float* xr = xb + (size_t)j * Edim;
    a0 += wgt * xr[2 * m0];
    a1 += wgt * xr[2 * m1];
  }
  const float v0 = graw[m0], v1 = graw[m1];
  const float g0 = fmaxf(v0, 0.0f) + log1pf(__expf(-fabsf(v0)));
  const float g1 = fmaxf(v1, 0.0f) + log1pf(__expf(-fabsf(v1)));
  const size_t o = ((size_t)(b * Tdim + i)) * Edim;
  const float* xi = xb + (size_t)i * Edim;
  out[o + 2 * m0]     = xi[2 * m0];
  out[o + 2 * m0 + 1] = a0 * sinv * g0;
  out[o + 2 * m1]     = xi[2 * m1];
  out[o + 2 * m1 + 1] = a1 * sinv * g1;
}

extern "C" void kernel_launch(void* const* d_in, const int* in_sizes, int n_in,
                              void* d_out, int out_size, void* d_ws, size_t ws_size,
                              hipStream_t stream) {
  const float* x = (const float*)d_in[0];
  // d_in[1] is the triu mask: always upper-triangular by construction; folded analytically.
  const float* gate_raw = (const float*)d_in[2];
  float* out = (float*)d_out;

  const size_t XcT_bytes  = (size_t)Bdim * Mdim * Tdim * 2;   // 16 MiB
  const size_t Kswz_bytes = (size_t)NTILES * 16384;           // 16.5 MiB
  const size_t inv_bytes  = (size_t)Tdim * 4;                 // 16 KiB
  const size_t flag_bytes = 512 * 4;                          // 2 KiB
  const size_t need = XcT_bytes + Kswz_bytes + inv_bytes + flag_bytes;

  if (ws_size < need) {
    fallback_kernel<<<dim3(Tdim, Bdim), 256, 0, stream>>>(x, gate_raw, out);
    return;
  }

  char* ws = (char*)d_ws;
  unsigned short* XcT  = (unsigned short*)ws;
  unsigned short* Kswz = (unsigned short*)(ws + XcT_bytes);
  float* inv_s         = (float*)(ws + XcT_bytes + Kswz_bytes);
  int* flags           = (int*)(ws + XcT_bytes + Kswz_bytes + inv_bytes);

  hipMemsetAsync(flags, 0, flag_bytes, stream);
  prep_kernel<<<dim3(2 * Tdim), 256, 0, stream>>>(x, inv_s, XcT);
  packK_kernel<<<dim3(NTILES), 256, 0, stream>>>(inv_s, Kswz);
  gemm_kernel<<<dim3(1024), 256, 0, stream>>>(Kswz, XcT, x, gate_raw, out, flags);
}

// Round 7
// 221.923 us; speedup vs baseline: 2.1249x; 2.1249x over previous
//
#include <hip/hip_runtime.h>
#include <cstdint>
#include <cstddef>

// Problem constants (reference: B=4, T=4096, E=1024, M=E/2=512)
#define Tdim 4096
#define Bdim 4
#define Edim 1024
#define Mdim 512
#define EPSF 1e-6f
#define NTILES 1056  // sum over p of (64-2p) = S(32), panels store only k>=i0

typedef __bf16 bf16x8 __attribute__((ext_vector_type(8)));
typedef float f32x4 __attribute__((ext_vector_type(4)));

// S(p) = number of k64-tiles in panels [0,p) = p*(65-p)
__host__ __device__ __forceinline__ int panel_start(int p) { return p * (65 - p); }

// float -> bf16 bits, round-to-nearest-even (used in extract path)
__device__ __forceinline__ unsigned short f2bf(float f) {
  union { float f; unsigned int u; } a; a.f = f;
  unsigned int r = a.u + 0x7fffu + ((a.u >> 16) & 1u);
  return (unsigned short)(r >> 16);
}

// pack two f32 -> bf16x2 (round-half-up; 0.5-ulp bound, ties negligible here)
__device__ __forceinline__ unsigned int pack_bf16(float a, float b) {
  union { float f; unsigned int u; } ua, ub; ua.f = a; ub.f = b;
  // dst bytes [0,1,2,3] = [a.b2, a.b3, b.b2, b.b3]
  return __builtin_amdgcn_perm(ub.u + 0x8000u, ua.u + 0x8000u, 0x07060302u);
}

// bump kernel g(u) = exp(1 - 1/(1-u^2+eps)); reference's u>=1-EPS clamp can
// never fire for j<=T-1 (u_max = 1 - 1/horizon), so it is omitted.
__device__ __forceinline__ float kernel_g(float dj, float inv_h) {
  float u = fminf(dj * inv_h, 1.0f - EPSF);
  return __expf(1.0f - 1.0f / (1.0f - u * u + EPSF));
}

typedef void __attribute__((address_space(1)))* gas1;
typedef void __attribute__((address_space(3)))* las3;
// async global->LDS, 16B per lane; LDS dest = wave-uniform base + lane*16
__device__ __forceinline__ void load_lds16(const void* g, void* l) {
  __builtin_amdgcn_global_load_lds((gas1)(g), (las3)(l), 16, 0, 0);
}

// ---------------- prep: row sums (inv_s) AND Xc transpose ----------------
// grid 8192 x 256. Blocks [0,4096): rowsum only. Blocks [4096,8192):
// extract tile -> XcT[b][m][j] = bf16(x[b][j][2m]). (R3/R4-verified.)
__global__ __launch_bounds__(256) void prep_kernel(const float* __restrict__ x,
                                                   float* __restrict__ inv_s,
                                                   unsigned short* __restrict__ XcT) {
  __shared__ float smem[1104];  // extract: [0..1087] as ushort[32][68]; rowsum: [1088..1091]
  const int tid = threadIdx.x;
  const int id = blockIdx.x;
  if (id < Tdim) {
    // ---- rowsum for K row i (same summation order as R0 -> identical bits) ----
    const int i = id;
    const float inv_h = __fdividef(1.0f, (float)(Tdim - i));
    float s = 0.0f;
    for (int j = i + tid; j < Tdim; j += 256)
      s += kernel_g((float)(j - i), inv_h);
#pragma unroll
    for (int off = 32; off; off >>= 1) s += __shfl_down(s, off);
    if ((tid & 63) == 0) smem[1088 + (tid >> 6)] = s;
    __syncthreads();
    if (tid == 0)
      inv_s[i] = __fdividef(
          1.0f, fmaxf(smem[1088] + smem[1089] + smem[1090] + smem[1091], EPSF));
  } else {
    // ---- extract tile: 64 j x 32 m ----
    const int eid = id - Tdim;
    const int j0 = (eid & 63) * 64;
    const int m0 = ((eid >> 6) & 15) * 32;
    const int b  = eid >> 10;
    unsigned short* Ls = reinterpret_cast<unsigned short*>(smem);  // [32][68]
    const int q = tid & 15;        // float4 chunk along e
    const int jbase = tid >> 4;    // 0..15
#pragma unroll
    for (int it = 0; it < 4; ++it) {
      const int jj = jbase + it * 16;
      const size_t off = ((size_t)(b * Tdim + j0 + jj)) * Edim + 2 * m0 + 4 * q;
      const float4 v = *reinterpret_cast<const float4*>(&x[off]);
      Ls[(2 * q) * 68 + jj]     = f2bf(v.x);   // even channel of m0+2q
      Ls[(2 * q + 1) * 68 + jj] = f2bf(v.z);   // even channel of m0+2q+1
    }
    __syncthreads();
    const int ch = tid & 15;
    const int mb = tid >> 4;
#pragma unroll
    for (int it = 0; it < 2; ++it) {
      const int m = mb + it * 16;
      ushort4 uv;
      uv.x = Ls[m * 68 + 4 * ch];
      uv.y = Ls[m * 68 + 4 * ch + 1];
      uv.z = Ls[m * 68 + 4 * ch + 2];
      uv.w = Ls[m * 68 + 4 * ch + 3];
      *reinterpret_cast<ushort4*>(
          &XcT[((size_t)(b * Mdim + m0 + m)) * Tdim + j0 + 4 * ch]) = uv;
    }
  }
}

// ---------------- packK: K in MFMA-fragment order (R3-verified, unchanged) --------
__global__ __launch_bounds__(256) void packK_kernel(const float* __restrict__ inv_s,
                                                    unsigned short* __restrict__ Kswz) {
  const int id = blockIdx.x;  // 0..NTILES-1
  int p = 0;
  while (id >= (p + 1) * (64 - p)) ++p;   // S(p+1) = (p+1)*(64-p)
  const int jt = id - panel_start(p);
  const int i0 = p * 128;
  const int jb0 = i0 + jt * 64;
  unsigned short* dst = Kswz + (size_t)id * 8192;  // 16 KB per (p,jt) tile
  const int tid = threadIdx.x;
#pragma unroll
  for (int ss = 0; ss < 4; ++ss) {
    const int G = ss * 256 + tid;          // chunk index 0..1023
    const int lane = G & 63;
    const int kk = (G >> 6) & 1;
    const int r  = (G >> 7) & 3;
    const int h  = G >> 9;
    const int li = h * 64 + r * 16 + (lane & 15);
    const int i  = i0 + li;
    const float inv_h = __fdividef(1.0f, (float)(Tdim - i));
    const float sinv = inv_s[i];
    const int jb = jb0 + (kk * 4 + (lane >> 4)) * 8;
    float v[8];
#pragma unroll
    for (int e = 0; e < 8; ++e) {
      const int j = jb + e;
      v[e] = (j >= i) ? kernel_g((float)(j - i), inv_h) * sinv : 0.0f;
    }
    uint4 pk;
    pk.x = pack_bf16(v[0], v[1]);
    pk.y = pack_bf16(v[2], v[3]);
    pk.z = pack_bf16(v[4], v[5]);
    pk.w = pack_bf16(v[6], v[7]);
    *reinterpret_cast<uint4*>(&dst[(size_t)G * 8]) = pk;
  }
}

// ---------------- GEMM: phi[b,i,m] = K[i,:] @ Xc[b,:,m], fused output write --------
// IN-BLOCK SPLIT-K on R4's verified loop. R4's wall: the p=0 job is 64
// SERIAL iters and its anti-length partner dies after 2 -> ~62 iters at
// 1 wave/SIMD, 2480 cyc/iter vs 621 cyc MFMA issue. Fix: 512 threads /
// 8 waves; group 0 (waves 0-3) computes k-tiles [0,nh), group 1 (waves
// 4-7) [nh,2nh), nh = 32-p (identical trip count -> shared s_barrier).
// Critical path 64 -> 32 iters, and the block ALWAYS has 2 waves/SIMD
// (both k-groups share the block lifetime); 4 waves/SIMD while the
// partner block lives. Partials combined through LDS (Bs reused) -- zero
// HBM, zero inter-block sync (the R6 global-combine disaster is avoided).
// VGPR: plain __launch_bounds__(512) -- NO min-waves arg (R5: (512,4)
// forced 64 VGPR -> full spill -> 138us). R4's loop body compiled to 104.
// LDS 2grp x 2buf x 16KB = 64KB -> 2 blocks/CU when VGPR<=128.
// Per-group per-iter schedule = R4's verified GHALF: counted vmcnt(8)
// (drains B(t)x4, leaves A(t)x8 in flight), raw s_barrier +
// sched_barrier(0), stage B(t+1), A(t+1) register ping-pong, uniform
// clamped tail loads (branch-free vmcnt).
// Anti-length pairing unchanged: CU c gets blocks {c,c+256} = panels
// (g,31-g): nh totals (32-g)+(1+g) = 33 slots/CU, exactly uniform.
__global__ __launch_bounds__(512) void gemm_kernel(
    const unsigned short* __restrict__ Kswz,
    const unsigned short* __restrict__ XcT,
    const float* __restrict__ x,
    const float* __restrict__ graw,
    float* __restrict__ out) {
  __shared__ unsigned short Bs[2][2][128 * 64];  // [grp][buf], swizzled 16B slots
  const int id = blockIdx.x;           // 0..511
  int p;
  if (id < 256) p = id >> 4;
  else          p = 31 - ((id - 256) >> 4);
  const int mb = id & 15;
  const int i0 = p * 128;
  const int m0 = (mb & 3) * 128;
  const int b  = mb >> 2;
  const int tid = threadIdx.x;
  const int w = tid >> 6;       // 0..7
  const int grp = w >> 2;       // k-split group
  const int wl = w & 3;         // wave within group
  const int l = tid & 63;
  const int wr = wl >> 1, wc = wl & 1;
  const unsigned short* Brow = XcT + ((size_t)b * Mdim + m0) * Tdim;
  const int srow  = l >> 3;                   // row within 8-row group
  const int sslot = l & 7;                    // linear 16B slot this lane fills
  const int schunk = (sslot ^ srow) * 8;      // swizzled source chunk (bf16 units)
  // A panel base for this wave's row-half and lane (units: shorts).
  // Fragment (r,kk) of panel-relative k-tile tt is at Apan + tt*8192 + (r*2+kk)*512.
  const unsigned short* Apan =
      Kswz + (size_t)panel_start(p) * 8192 + (size_t)(wr * 8) * 512 + (size_t)l * 8;

  f32x4 acc[4][4] = {};
  const int nh = 32 - p;           // per-group trip count (>= 1)
  const int tbase = grp * nh;      // group's first panel-relative k-tile
  const int lr16 = l & 15;
  const int kq = l >> 4;  // 0..3: which 16B chunk quarter of the k-dim

  // ---- prologue: B(0) FIRST (older in vmcnt order), then A(0). "" fences
  // stop the compiler reordering loads across group edges.
#pragma unroll
  for (int q = 0; q < 4; ++q) {
    const int rr = (wl * 4 + q) * 8 + srow;
    load_lds16(Brow + (size_t)rr * Tdim + (i0 + tbase * 64 + schunk),
               &Bs[grp][0][(wl * 4 + q) * 512]);
  }
  asm volatile("" ::: "memory");
  bf16x8 af0[2][4], af1[2][4];
#pragma unroll
  for (int r = 0; r < 4; ++r) {
    af0[0][r] = *reinterpret_cast<const bf16x8*>(Apan + (size_t)tbase * 8192 + (r * 2 + 0) * 512);
    af0[1][r] = *reinterpret_cast<const bf16x8*>(Apan + (size_t)tbase * 8192 + (r * 2 + 1) * 512);
  }
  asm volatile("" ::: "memory");

  // Per-iter vmcnt math: at top of iter t, outstanding = B(t)x4 (older) +
  // A(t)x8 (younger). vmcnt(8) completes exactly B(t); A(t) stays in flight
  // (compiler inserts its own vmcnt before the first MFMA using afC).
#define GHALF(tc, afC, afN)                                                       \
  do {                                                                            \
    asm volatile("s_waitcnt vmcnt(8)" ::: "memory");                              \
    __builtin_amdgcn_s_barrier();                                                 \
    __builtin_amdgcn_sched_barrier(0);                                            \
    /* stage B(tc+1) (clamped dead write at tail keeps vmcnt uniform) */          \
    {                                                                             \
      const int ts = (tc) + 1;                                                    \
      const int tt = tbase + ((ts < nh) ? ts : nh - 1);                           \
      unsigned short* bdst = Bs[grp][ts & 1];                                     \
      _Pragma("unroll")                                                           \
      for (int q = 0; q < 4; ++q) {                                               \
        const int rr = (wl * 4 + q) * 8 + srow;                                   \
        load_lds16(Brow + (size_t)rr * Tdim + (i0 + tt * 64 + schunk),            \
                   &bdst[(wl * 4 + q) * 512]);                                    \
      }                                                                           \
    }                                                                             \
    /* prefetch A(tc+1) into afN (clamped dead load at tail) */                   \
    {                                                                             \
      const int tpre = tbase + (((tc) + 1 < nh) ? (tc) + 1 : nh - 1);             \
      const unsigned short* Ap = Apan + (size_t)tpre * 8192;                      \
      _Pragma("unroll")                                                           \
      for (int r = 0; r < 4; ++r) {                                               \
        afN[0][r] = *reinterpret_cast<const bf16x8*>(Ap + (r * 2 + 0) * 512);     \
        afN[1][r] = *reinterpret_cast<const bf16x8*>(Ap + (r * 2 + 1) * 512);     \
      }                                                                           \
    }                                                                             \
    /* compute tile tc from Bs[grp][tc&1] + afC */                                \
    {                                                                             \
      const unsigned short* bsrc = Bs[grp][(tc) & 1];                             \
      _Pragma("unroll")                                                           \
      for (int kk = 0; kk < 2; ++kk) {                                            \
        bf16x8 bfr[4];                                                            \
        const int chunk = kk * 4 + kq;                                            \
        const int slot = (chunk ^ (lr16 & 7)) * 8; /* un-swizzle */               \
        _Pragma("unroll")                                                         \
        for (int c = 0; c < 4; ++c)                                               \
          bfr[c] = *reinterpret_cast<const bf16x8*>(                              \
              &bsrc[(wc * 64 + c * 16 + lr16) * 64 + slot]);                      \
        _Pragma("unroll")                                                         \
        for (int r = 0; r < 4; ++r)                                               \
          _Pragma("unroll")                                                       \
          for (int c = 0; c < 4; ++c)                                             \
            acc[r][c] = __builtin_amdgcn_mfma_f32_16x16x32_bf16(                  \
                afC[kk][r], bfr[c], acc[r][c], 0, 0, 0);                          \
      }                                                                           \
    }                                                                             \
  } while (0)

  for (int t = 0; t + 1 < nh; t += 2) {
    GHALF(t, af0, af1);
    GHALF(t + 1, af1, af0);
  }
  if (nh & 1) GHALF(nh - 1, af0, af1);
#undef GHALF

  // ---- split-k combine through LDS. First __syncthreads drains the tail's
  // dead staging loads (vmcnt0) + all waves' ds_reads before Bs is reused.
  // grp1 publishes acc (64 KB exactly), grp0 adds and runs the epilogue.
  // Slot XOR keeps each thread's 16 f32x4 spread across 16B-slots.
  __syncthreads();
  float* Cb = reinterpret_cast<float*>(&Bs[0][0][0]);  // 64 KB = 256 thr x 16 f32x4
  const int tig = wl * 64 + l;  // thread index within group, 0..255
  if (grp == 1) {
#pragma unroll
    for (int r = 0; r < 4; ++r)
#pragma unroll
      for (int c = 0; c < 4; ++c) {
        const int cc = r * 4 + c;
        const int slot = tig * 16 + (cc ^ (tig & 15));
        *reinterpret_cast<f32x4*>(&Cb[slot * 4]) = acc[r][c];
      }
  }
  __syncthreads();
  if (grp == 0) {
#pragma unroll
    for (int r = 0; r < 4; ++r)
#pragma unroll
      for (int c = 0; c < 4; ++c) {
        const int cc = r * 4 + c;
        const int slot = tig * 16 + (cc ^ (tig & 15));
        const f32x4 part = *reinterpret_cast<const f32x4*>(&Cb[slot * 4]);
        acc[r][c] += part;
      }

    // fused epilogue: C/D layout col=lane&15 (m), row=(lane>>4)*4+reg (i).
    // out even = x even (exact fp32 passthrough), odd = phi*softplus(graw[m]).
    const int lr = l & 15;
    const int lq = l >> 4;
    float gm[4];
#pragma unroll
    for (int c = 0; c < 4; ++c) {
      const float v = graw[m0 + wc * 64 + c * 16 + lr];
      gm[c] = fmaxf(v, 0.0f) + __logf(1.0f + __expf(-fabsf(v)));  // stable softplus
    }
#pragma unroll
    for (int r = 0; r < 4; ++r) {
      const int ii = i0 + wr * 64 + r * 16 + lq * 4;
#pragma unroll
      for (int c = 0; c < 4; ++c) {
        const int m = m0 + wc * 64 + c * 16 + lr;
#pragma unroll
        for (int v = 0; v < 4; ++v) {
          const size_t o = ((size_t)(b * Tdim + ii + v)) * Edim + 2 * m;
          const float2 xv = *reinterpret_cast<const float2*>(&x[o]);
          float2 res;
          res.x = xv.x;
          res.y = acc[r][c][v] * gm[c];
          *reinterpret_cast<float2*>(&out[o]) = res;
        }
      }
    }
  }
}

// ---------------- slow-but-correct fallback (only if ws too small) ----------------
__global__ __launch_bounds__(256) void fallback_kernel(const float* __restrict__ x,
                                                       const float* __restrict__ graw,
                                                       float* __restrict__ out) {
  const int i = blockIdx.x, b = blockIdx.y, tid = threadIdx.x;
  const float inv_h = 1.0f / (float)(Tdim - i);
  float s = 0.0f;
  for (int j = i + tid; j < Tdim; j += 256)
    s += kernel_g((float)(j - i), inv_h);
#pragma unroll
  for (int off = 32; off; off >>= 1) s += __shfl_down(s, off);
  __shared__ float red[4];
  __shared__ float sinv_sh;
  if ((tid & 63) == 0) red[tid >> 6] = s;
  __syncthreads();
  if (tid == 0) sinv_sh = 1.0f / (red[0] + red[1] + red[2] + red[3]);
  __syncthreads();
  const float sinv = sinv_sh;
  const float* xb = x + (size_t)b * Tdim * Edim;
  float a0 = 0.0f, a1 = 0.0f;
  const int m0 = tid, m1 = tid + 256;
  for (int j = i; j < Tdim; ++j) {
    const float wgt = kernel_g((float)(j - i), inv_h);
    const float* xr = xb + (size_t)j * Edim;
    a0 += wgt * xr[2 * m0];
    a1 += wgt * xr[2 * m1];
  }
  const float v0 = graw[m0], v1 = graw[m1];
  const float g0 = fmaxf(v0, 0.0f) + log1pf(__expf(-fabsf(v0)));
  const float g1 = fmaxf(v1, 0.0f) + log1pf(__expf(-fabsf(v1)));
  const size_t o = ((size_t)(b * Tdim + i)) * Edim;
  const float* xi = xb + (size_t)i * Edim;
  out[o + 2 * m0]     = xi[2 * m0];
  out[o + 2 * m0 + 1] = a0 * sinv * g0;
  out[o + 2 * m1]     = xi[2 * m1];
  out[o + 2 * m1 + 1] = a1 * sinv * g1;
}

extern "C" void kernel_launch(void* const* d_in, const int* in_sizes, int n_in,
                              void* d_out, int out_size, void* d_ws, size_t ws_size,
                              hipStream_t stream) {
  const float* x = (const float*)d_in[0];
  // d_in[1] is the triu mask: always upper-triangular by construction; folded analytically.
  const float* gate_raw = (const float*)d_in[2];
  float* out = (float*)d_out;

  const size_t XcT_bytes  = (size_t)Bdim * Mdim * Tdim * 2;   // 16 MiB
  const size_t Kswz_bytes = (size_t)NTILES * 16384;           // 16.5 MiB
  const size_t inv_bytes  = (size_t)Tdim * 4;                 // 16 KiB
  const size_t need = XcT_bytes + Kswz_bytes + inv_bytes;

  if (ws_size < need) {
    fallback_kernel<<<dim3(Tdim, Bdim), 256, 0, stream>>>(x, gate_raw, out);
    return;
  }

  char* ws = (char*)d_ws;
  unsigned short* XcT  = (unsigned short*)ws;
  unsigned short* Kswz = (unsigned short*)(ws + XcT_bytes);
  float* inv_s         = (float*)(ws + XcT_bytes + Kswz_bytes);

  prep_kernel<<<dim3(2 * Tdim), 256, 0, stream>>>(x, inv_s, XcT);
  packK_kernel<<<dim3(NTILES), 256, 0, stream>>>(inv_s, Kswz);
  gemm_kernel<<<dim3(512), 512, 0, stream>>>(Kswz, XcT, x, gate_raw, out);
}